// Round 24
// baseline (50.165 us; speedup 1.0000x reference)
//
#include <hip/hip_runtime.h>

typedef __bf16 bf16_t;
typedef __bf16 bf16x4 __attribute__((ext_vector_type(4)));
typedef __bf16 bf16x8 __attribute__((ext_vector_type(8)));
typedef float  f32x4  __attribute__((ext_vector_type(4)));

#define B_SZ  16
#define L_SEQ 2048
#define D_H   64
#define QB    64
#define KB    128
#define NQT   (L_SEQ / QB)   // 32

// softmax is over (S/8); fold log2(e)/8 into Q so MFMA output is in log2 units
#define QSCALE 0.18033688011112043f

// ---------------- producer/consumer kernel, dual-q-group consumers ----------------
// r20 scaffold: 512 blocks (balanced qt pairing, 2 batches/XCD), 2 blocks/CU.
// Block = 256 threads: waves 0-1 consumers (32 q-rows each, 2 groups; one ds_read
// feeds two MFMAs -> LDS-pipe issue per unit work halved), waves 2-3 producers.
__global__ __launch_bounds__(256, 2)
void attn_pc2_kernel(const float* __restrict__ Qg, const float* __restrict__ Kg,
                     const float* __restrict__ Vg, float* __restrict__ Og)
{
    const int lin  = blockIdx.x;          // 0..511
    const int xcd  = lin & 7;
    const int slot = lin >> 3;            // 0..63
    const int half = slot >> 5;
    const int qi   = slot & 31;
    const int b    = xcd * 2 + half;      // 2 batches per XCD -> K/V L2-resident
    const int qt   = half ? qi : (31 - qi);

    const int tid  = threadIdx.x;
    const int wave = tid >> 6;            // 0..3
    const int lane = tid & 63;
    const int lg   = lane >> 4;
    const int lc   = lane & 15;

    __shared__ __align__(16) bf16_t K_lds[2][KB][72];      // 36 KB
    __shared__ __align__(16) bf16_t Vt_lds[2][D_H][136];   // 34 KB

    const size_t bbase = (size_t)b * L_SEQ * D_H;
    const int nkt = (qt + 2) >> 1;        // number of 128-wide K tiles (last masked)

    if (wave >= 2) {
        // ================= PRODUCER (waves 2-3, 128 threads) =================
        const int pt   = tid - 128;       // 0..127
        const int vkb  = pt & 31;         // k-block (4 rows) 0..31
        const int vdg2 = pt >> 5;         // 0..3 -> d-blocks vdg2 + 4*d2
        const int vpos = ((vkb >> 3) << 5) + ((vkb & 3) << 3) + (((vkb >> 2) & 1) << 2);

        f32x4 kreg[16], vreg[16];

        auto stageK = [&](int kt, int buf) {
            const int kbase = kt * KB;
#pragma unroll
            for (int i = 0; i < 16; ++i) {
                const int f = i * 128 + pt;
                const int r = f >> 4, c4 = (f & 15) * 4;
                kreg[i] = *reinterpret_cast<const f32x4*>(Kg + bbase + (size_t)(kbase + r) * D_H + c4);
            }
#pragma unroll
            for (int i = 0; i < 16; ++i) {
                const int f = i * 128 + pt;
                const int r = f >> 4, c4 = (f & 15) * 4;
                bf16x4 k4 = { (bf16_t)kreg[i][0], (bf16_t)kreg[i][1], (bf16_t)kreg[i][2], (bf16_t)kreg[i][3] };
                *reinterpret_cast<bf16x4*>(&K_lds[buf][r][c4]) = k4;
            }
        };
        auto stageV = [&](int kt, int buf) {
            const int kbase = kt * KB;
#pragma unroll
            for (int d2 = 0; d2 < 4; ++d2) {
                const int db = vdg2 + d2 * 4;
#pragma unroll
                for (int i = 0; i < 4; ++i)
                    vreg[d2 * 4 + i] = *reinterpret_cast<const f32x4*>(
                        Vg + bbase + (size_t)(kbase + vkb * 4 + i) * D_H + db * 4);
            }
#pragma unroll
            for (int d2 = 0; d2 < 4; ++d2) {
                const int db = vdg2 + d2 * 4;
#pragma unroll
                for (int j = 0; j < 4; ++j) {
                    bf16x4 cj = { (bf16_t)vreg[d2 * 4 + 0][j], (bf16_t)vreg[d2 * 4 + 1][j],
                                  (bf16_t)vreg[d2 * 4 + 2][j], (bf16_t)vreg[d2 * 4 + 3][j] };
                    *reinterpret_cast<bf16x4*>(&Vt_lds[buf][db * 4 + j][vpos]) = cj;
                }
            }
        };

        stageK(0, 0); stageV(0, 0);
        __syncthreads();                                   // prologue barrier
        for (int kt = 0; kt < nkt; ++kt) {
            if (kt + 1 < nkt) { stageK(kt + 1, (kt + 1) & 1); stageV(kt + 1, (kt + 1) & 1); }
            __syncthreads();                               // tile kt+1 ready / kt consumed
        }
    } else {
        // ================= CONSUMER (waves 0-1, 32 q-rows each) =================
        const int qrow0 = qt * QB + wave * 32 + lc;        // group g covers qrow0 + g*16
        bf16x8 qa[2][2];                                   // [group][h]
#pragma unroll
        for (int g = 0; g < 2; ++g)
#pragma unroll
            for (int h = 0; h < 2; ++h) {
                const float* qp = Qg + bbase + (size_t)(qrow0 + g * 16) * D_H + h * 32 + lg * 8;
                const f32x4 f0 = *reinterpret_cast<const f32x4*>(qp);
                const f32x4 f1 = *reinterpret_cast<const f32x4*>(qp + 4);
                bf16x8 a;
#pragma unroll
                for (int j = 0; j < 4; ++j) { a[j] = (bf16_t)(f0[j] * QSCALE); a[4 + j] = (bf16_t)(f1[j] * QSCALE); }
                qa[g][h] = a;
            }

        f32x4 o[2][4];
        float m[2], l[2];
#pragma unroll
        for (int g = 0; g < 2; ++g) {
#pragma unroll
            for (int dt = 0; dt < 4; ++dt) o[g][dt] = (f32x4){0.f, 0.f, 0.f, 0.f};
            m[g] = -1e30f; l[g] = 0.f;
        }

        __syncthreads();                                   // prologue barrier
        for (int kt = 0; kt < nkt; ++kt) {
            const bool last = (kt == nkt - 1);
            const int kbase = kt * KB;
            const int cur   = kt & 1;

            // ---- S^T = K Q^T: one kb read feeds both q-groups ----
            f32x4 sc[2][8];
            __builtin_amdgcn_s_setprio(1);
#pragma unroll
            for (int n = 0; n < 8; ++n) {
                f32x4 a0 = (f32x4){0.f, 0.f, 0.f, 0.f};
                f32x4 a1 = (f32x4){0.f, 0.f, 0.f, 0.f};
#pragma unroll
                for (int h = 0; h < 2; ++h) {
                    const bf16x8 kb = *reinterpret_cast<const bf16x8*>(&K_lds[cur][n * 16 + lc][h * 32 + lg * 8]);
                    a0 = __builtin_amdgcn_mfma_f32_16x16x32_bf16(kb, qa[0][h], a0, 0, 0, 0);
                    a1 = __builtin_amdgcn_mfma_f32_16x16x32_bf16(kb, qa[1][h], a1, 0, 0, 0);
                }
                sc[0][n] = a0; sc[1][n] = a1;
            }
            __builtin_amdgcn_s_setprio(0);
            if (last) {
#pragma unroll
                for (int g = 0; g < 2; ++g) {
                    const int qr = qrow0 + g * 16;
#pragma unroll
                    for (int n = 0; n < 8; ++n)
#pragma unroll
                        for (int r = 0; r < 4; ++r)
                            if (kbase + n * 16 + lg * 4 + r > qr) sc[g][n][r] = -1e30f;
                }
            }

            // ---- defer-max online softmax, independent per q-group ----
            bf16x8 w[2][4];
#pragma unroll
            for (int g = 0; g < 2; ++g) {
                float mxp = fmaxf(fmaxf(sc[g][0][0], sc[g][0][1]), fmaxf(sc[g][0][2], sc[g][0][3]));
#pragma unroll
                for (int n = 1; n < 8; ++n)
                    mxp = fmaxf(mxp, fmaxf(fmaxf(sc[g][n][0], sc[g][n][1]), fmaxf(sc[g][n][2], sc[g][n][3])));
                if (!__all(mxp <= m[g] + 8.0f)) {
                    float mx = mxp;
                    mx = fmaxf(mx, __shfl_xor(mx, 16));
                    mx = fmaxf(mx, __shfl_xor(mx, 32));
                    const float mn = fmaxf(m[g], mx);
                    const float alpha = exp2f(m[g] - mn);
                    m[g] = mn;
                    l[g] *= alpha;
#pragma unroll
                    for (int dt = 0; dt < 4; ++dt)
#pragma unroll
                        for (int r = 0; r < 4; ++r) o[g][dt][r] *= alpha;
                }
                float rs = 0.f;
#pragma unroll
                for (int n = 0; n < 8; ++n) {
                    const float p0 = exp2f(sc[g][n][0] - m[g]), p1 = exp2f(sc[g][n][1] - m[g]);
                    const float p2 = exp2f(sc[g][n][2] - m[g]), p3 = exp2f(sc[g][n][3] - m[g]);
                    rs += (p0 + p1) + (p2 + p3);
                    const int wi = n >> 1, off = (n & 1) * 4;
                    w[g][wi][off + 0] = (bf16_t)p0; w[g][wi][off + 1] = (bf16_t)p1;
                    w[g][wi][off + 2] = (bf16_t)p2; w[g][wi][off + 3] = (bf16_t)p3;
                }
                l[g] += rs;
            }

            // ---- O^T += V^T P : one vb read feeds both q-groups ----
            __builtin_amdgcn_s_setprio(1);
#pragma unroll
            for (int ks = 0; ks < 4; ++ks) {
#pragma unroll
                for (int dt = 0; dt < 4; ++dt) {
                    const bf16x8 vb = *reinterpret_cast<const bf16x8*>(&Vt_lds[cur][dt * 16 + lc][ks * 32 + lg * 8]);
                    o[0][dt] = __builtin_amdgcn_mfma_f32_16x16x32_bf16(vb, w[0][ks], o[0][dt], 0, 0, 0);
                    o[1][dt] = __builtin_amdgcn_mfma_f32_16x16x32_bf16(vb, w[1][ks], o[1][dt], 0, 0, 0);
                }
            }
            __builtin_amdgcn_s_setprio(0);

            __syncthreads();                               // tile kt consumed / kt+1 ready
        }

        // ---- epilogue: per group, reduce per-lane l, then O = O^T / l ----
#pragma unroll
        for (int g = 0; g < 2; ++g) {
            float lr = l[g];
            lr += __shfl_xor(lr, 16);
            lr += __shfl_xor(lr, 32);
            const float inv = 1.0f / lr;
#pragma unroll
            for (int dt = 0; dt < 4; ++dt) {
                f32x4 val = { o[g][dt][0] * inv, o[g][dt][1] * inv, o[g][dt][2] * inv, o[g][dt][3] * inv };
                *reinterpret_cast<f32x4*>(Og + bbase + (size_t)(qrow0 + g * 16) * D_H + dt * 16 + lg * 4) = val;
            }
        }
    }
}

extern "C" void kernel_launch(void* const* d_in, const int* in_sizes, int n_in,
                              void* d_out, int out_size, void* d_ws, size_t ws_size,
                              hipStream_t stream)
{
    const float* Q = (const float*)d_in[0];
    const float* K = (const float*)d_in[1];
    const float* V = (const float*)d_in[2];
    float* O = (float*)d_out;
    attn_pc2_kernel<<<dim3(NQT * B_SZ), dim3(256), 0, stream>>>(Q, K, V, O);
}

// Round 25
// 33.919 us; speedup vs baseline: 1.4790x; 1.4790x over previous
//
#include <hip/hip_runtime.h>

typedef __bf16 bf16_t;
typedef __bf16 bf16x4 __attribute__((ext_vector_type(4)));
typedef __bf16 bf16x8 __attribute__((ext_vector_type(8)));
typedef float  f32x4  __attribute__((ext_vector_type(4)));

#define B_SZ  16
#define L_SEQ 2048
#define D_H   64
#define QB    64
#define KB    128
#define NQT   (L_SEQ / QB)   // 32

// softmax is over (S/8); fold log2(e)/8 into Q so MFMA output is in log2 units
#define QSCALE 0.18033688011112043f

// ---------------- producer/consumer kernel (round-20 best: 33.8 us) ----------------
// 512 blocks (balanced qt pairing, 2 batches/XCD), 8 waves each, 2 blocks/CU.
// waves 0-3 (consumers): compute engine, 16 q-rows per wave, NO global K/V access.
// waves 4-7 (producers): staging engine on 256 threads, NO FLOPs.
// Double-buffered LDS; 1 barrier/iter; producer stages tile j+1 while consumers compute j.
__global__ __launch_bounds__(512, 4)
void attn_pc_kernel(const float* __restrict__ Qg, const float* __restrict__ Kg,
                    const float* __restrict__ Vg, float* __restrict__ Og)
{
    const int lin  = blockIdx.x;          // 0..511
    const int xcd  = lin & 7;
    const int slot = lin >> 3;            // 0..63
    const int half = slot >> 5;
    const int qi   = slot & 31;
    const int b    = xcd * 2 + half;      // 2 batches per XCD -> K/V L2-resident
    const int qt   = half ? qi : (31 - qi);

    const int tid  = threadIdx.x;
    const int wave = tid >> 6;            // 0..7
    const int lane = tid & 63;
    const int lg   = lane >> 4;
    const int lc   = lane & 15;

    __shared__ __align__(16) bf16_t K_lds[2][KB][72];      // padded layout, 36 KB
    __shared__ __align__(16) bf16_t Vt_lds[2][D_H][136];   // transposed+phi, 34 KB

    const size_t bbase = (size_t)b * L_SEQ * D_H;
    const int nkt = (qt + 2) >> 1;        // number of 128-wide K tiles (last masked)

    if (wave >= 4) {
        // ================= PRODUCER (waves 4-7, 256 threads) =================
        const int pt   = tid - 256;       // 0..255
        const int vkb  = pt & 31;         // k-block (4 rows) 0..31
        const int vdg  = pt >> 5;         // 0..7 -> d-blocks vdg, vdg+8
        const int vpos = ((vkb >> 3) << 5) + ((vkb & 3) << 3) + (((vkb >> 2) & 1) << 2);

        f32x4 kreg[8], vreg[8];

        auto issueK = [&](int kt) {
            const int kbase = kt * KB;
#pragma unroll
            for (int i = 0; i < 8; ++i) {
                const int f = i * 256 + pt;
                const int r = f >> 4, c4 = (f & 15) * 4;
                kreg[i] = *reinterpret_cast<const f32x4*>(Kg + bbase + (size_t)(kbase + r) * D_H + c4);
            }
        };
        auto issueV = [&](int kt) {
            const int kbase = kt * KB;
#pragma unroll
            for (int d2 = 0; d2 < 2; ++d2)
#pragma unroll
                for (int i = 0; i < 4; ++i)
                    vreg[d2 * 4 + i] = *reinterpret_cast<const f32x4*>(
                        Vg + bbase + (size_t)(kbase + vkb * 4 + i) * D_H + (vdg + d2 * 8) * 4);
        };
        auto writeK = [&](int buf) {
#pragma unroll
            for (int i = 0; i < 8; ++i) {
                const int f = i * 256 + pt;
                const int r = f >> 4, c4 = (f & 15) * 4;
                bf16x4 k4 = { (bf16_t)kreg[i][0], (bf16_t)kreg[i][1], (bf16_t)kreg[i][2], (bf16_t)kreg[i][3] };
                *reinterpret_cast<bf16x4*>(&K_lds[buf][r][c4]) = k4;
            }
        };
        auto writeV = [&](int buf) {
#pragma unroll
            for (int d2 = 0; d2 < 2; ++d2) {
                const int db = vdg + d2 * 8;
#pragma unroll
                for (int j = 0; j < 4; ++j) {
                    bf16x4 cj = { (bf16_t)vreg[d2 * 4 + 0][j], (bf16_t)vreg[d2 * 4 + 1][j],
                                  (bf16_t)vreg[d2 * 4 + 2][j], (bf16_t)vreg[d2 * 4 + 3][j] };
                    *reinterpret_cast<bf16x4*>(&Vt_lds[buf][db * 4 + j][vpos]) = cj;
                }
            }
        };

        issueK(0); issueV(0); writeK(0); writeV(0);
        __syncthreads();                                   // prologue barrier
        for (int kt = 0; kt < nkt; ++kt) {
            if (kt + 1 < nkt) {
                issueK(kt + 1); issueV(kt + 1);
                writeK((kt + 1) & 1); writeV((kt + 1) & 1);
            }
            __syncthreads();                               // tile kt+1 ready / kt consumed
        }
    } else {
        // ================= CONSUMER (waves 0-3) =================
        const int qrow = qt * QB + wave * 16 + lc;
        bf16x8 qa[2];
#pragma unroll
        for (int h = 0; h < 2; ++h) {
            const float* qp = Qg + bbase + (size_t)qrow * D_H + h * 32 + lg * 8;
            const f32x4 f0 = *reinterpret_cast<const f32x4*>(qp);
            const f32x4 f1 = *reinterpret_cast<const f32x4*>(qp + 4);
            bf16x8 a;
#pragma unroll
            for (int j = 0; j < 4; ++j) { a[j] = (bf16_t)(f0[j] * QSCALE); a[4 + j] = (bf16_t)(f1[j] * QSCALE); }
            qa[h] = a;
        }

        f32x4 o[4];
#pragma unroll
        for (int dt = 0; dt < 4; ++dt) o[dt] = (f32x4){0.f, 0.f, 0.f, 0.f};
        float m = -1e30f, l = 0.f;        // per-lane l partial in frame m

        __syncthreads();                                   // prologue barrier
        for (int kt = 0; kt < nkt; ++kt) {
            const bool last = (kt == nkt - 1);
            const int kbase = kt * KB;
            const int cur   = kt & 1;

            // ---- S^T = K Q^T (log2 units): sc[n][r] = S[k=kbase+n*16+lg*4+r][q=qrow] ----
            f32x4 sc[8];
            __builtin_amdgcn_s_setprio(1);
#pragma unroll
            for (int n = 0; n < 8; ++n) {
                f32x4 acc = (f32x4){0.f, 0.f, 0.f, 0.f};
#pragma unroll
                for (int h = 0; h < 2; ++h) {
                    const bf16x8 kb = *reinterpret_cast<const bf16x8*>(&K_lds[cur][n * 16 + lc][h * 32 + lg * 8]);
                    acc = __builtin_amdgcn_mfma_f32_16x16x32_bf16(kb, qa[h], acc, 0, 0, 0);
                }
                sc[n] = acc;
            }
            __builtin_amdgcn_s_setprio(0);
            if (last) {
#pragma unroll
                for (int n = 0; n < 8; ++n)
#pragma unroll
                    for (int r = 0; r < 4; ++r)
                        if (kbase + n * 16 + lg * 4 + r > qrow) sc[n][r] = -1e30f;
            }

            // ---- defer-max online softmax (per-lane; cross-lane only on slow path) ----
            float mxp = fmaxf(fmaxf(sc[0][0], sc[0][1]), fmaxf(sc[0][2], sc[0][3]));
#pragma unroll
            for (int n = 1; n < 8; ++n)
                mxp = fmaxf(mxp, fmaxf(fmaxf(sc[n][0], sc[n][1]), fmaxf(sc[n][2], sc[n][3])));
            if (!__all(mxp <= m + 8.0f)) {
                float mx = mxp;
                mx = fmaxf(mx, __shfl_xor(mx, 16));
                mx = fmaxf(mx, __shfl_xor(mx, 32));
                const float mn = fmaxf(m, mx);
                const float alpha = exp2f(m - mn);
                m = mn;
                l *= alpha;
#pragma unroll
                for (int dt = 0; dt < 4; ++dt)
#pragma unroll
                    for (int r = 0; r < 4; ++r) o[dt][r] *= alpha;
            }
            // P packed directly into the PV B-operand layout (phi-permuted V^T)
            bf16x8 w[4];
            float rs = 0.f;
#pragma unroll
            for (int n = 0; n < 8; ++n) {
                const float p0 = exp2f(sc[n][0] - m), p1 = exp2f(sc[n][1] - m);
                const float p2 = exp2f(sc[n][2] - m), p3 = exp2f(sc[n][3] - m);
                rs += (p0 + p1) + (p2 + p3);
                const int wi = n >> 1, off = (n & 1) * 4;
                w[wi][off + 0] = (bf16_t)p0; w[wi][off + 1] = (bf16_t)p1;
                w[wi][off + 2] = (bf16_t)p2; w[wi][off + 3] = (bf16_t)p3;
            }
            l += rs;

            // ---- O^T += V^T P : P straight from registers ----
            __builtin_amdgcn_s_setprio(1);
#pragma unroll
            for (int ks = 0; ks < 4; ++ks) {
#pragma unroll
                for (int dt = 0; dt < 4; ++dt) {
                    const bf16x8 vb = *reinterpret_cast<const bf16x8*>(&Vt_lds[cur][dt * 16 + lc][ks * 32 + lg * 8]);
                    o[dt] = __builtin_amdgcn_mfma_f32_16x16x32_bf16(vb, w[ks], o[dt], 0, 0, 0);
                }
            }
            __builtin_amdgcn_s_setprio(0);

            __syncthreads();                               // tile kt consumed / kt+1 ready
        }

        // ---- epilogue: reduce per-lane l, then O = O^T / l ----
        float lr = l;
        lr += __shfl_xor(lr, 16);
        lr += __shfl_xor(lr, 32);
        const float inv = 1.0f / lr;
#pragma unroll
        for (int dt = 0; dt < 4; ++dt) {
            f32x4 val = { o[dt][0] * inv, o[dt][1] * inv, o[dt][2] * inv, o[dt][3] * inv };
            *reinterpret_cast<f32x4*>(Og + bbase + (size_t)qrow * D_H + dt * 16 + lg * 4) = val;
        }
    }
}

extern "C" void kernel_launch(void* const* d_in, const int* in_sizes, int n_in,
                              void* d_out, int out_size, void* d_ws, size_t ws_size,
                              hipStream_t stream)
{
    const float* Q = (const float*)d_in[0];
    const float* K = (const float*)d_in[1];
    const float* V = (const float*)d_in[2];
    float* O = (float*)d_out;
    attn_pc_kernel<<<dim3(NQT * B_SZ), dim3(512), 0, stream>>>(Q, K, V, O);
}